// Round 8
// baseline (484.037 us; speedup 1.0000x reference)
//
#include <hip/hip_runtime.h>
#include <cstdint>
#include <cstddef>

// ---------------- problem constants ----------------
#define B_   2
#define T_   2048
#define D_   2048
#define H_   16
#define DH_  128
#define DQ_  1024
#define DKV_ 512
#define DR_  64
#define M_   4096            // B_*T_
#define SCALE_ 0.07216878364870323f   // 1/sqrt(DH_+DR_)
#define SC2_   0.10412808709930322f   // SCALE_ * log2(e)
#define LN_BASE_ 13.122363377404328f  // ln(500000)

typedef unsigned short u16;
typedef __attribute__((ext_vector_type(8))) short short8;   // 8 bf16 (4 VGPRs)
typedef __attribute__((ext_vector_type(4))) float f32x4;    // 4 fp32 acc

__device__ __forceinline__ float b2f(u16 u) { return __uint_as_float(((uint32_t)u) << 16); }
__device__ __forceinline__ u16 f2b(float f) {            // RNE
    uint32_t x = __float_as_uint(f);
    return (u16)((x + 0x7fffu + ((x >> 16) & 1u)) >> 16);
}
__device__ __forceinline__ u16 f2b_fast(float f) {       // round-up-ties, 2 ops
    return (u16)((__float_as_uint(f) + 0x8000u) >> 16);
}

// ---------------- fp32 -> bf16 elementwise cast -----------------------------
__global__ __launch_bounds__(256) void cast_f2b_k(const float* __restrict__ in,
                                                  u16* __restrict__ out) {
    const int i = (blockIdx.x * 256 + threadIdx.x) * 4;
    const float4 v = *(const float4*)(in + i);
    ushort4 o;
    o.x = f2b(v.x); o.y = f2b(v.y); o.z = f2b(v.z); o.w = f2b(v.w);
    *(ushort4*)(out + i) = o;
}

// ---------- fused weight transpose+cast: 8 weights in one launch ------------
struct TPack {
    const float* src[8];
    u16*         dst[8];
    int K[8];      // src rows
    int N[8];      // src cols (real)
    int ntx[8];    // tiles along out-row dim (covers padded N)
    int start[9];  // cumulative tile offsets
};

__global__ __launch_bounds__(256) void transpose_all(TPack p) {
    __shared__ float tile[32][33];
    const int bid = blockIdx.x;
    int w = 0;
#pragma unroll
    for (int i = 1; i < 8; ++i) if (bid >= p.start[i]) w = i;
    const int lt = bid - p.start[w];
    const int bx = lt % p.ntx[w], by = lt / p.ntx[w];
    const float* in = p.src[w];
    u16* out = p.dst[w];
    const int K = p.K[w], N = p.N[w];
    const int k0 = by * 32, n0 = bx * 32;
    const int tx = threadIdx.x, ty = threadIdx.y;  // (32,8)
#pragma unroll
    for (int i = 0; i < 4; ++i) {
        int k = k0 + ty + i * 8;
        int n = n0 + tx;
        tile[ty + i * 8][tx] = (n < N) ? in[(size_t)k * N + n] : 0.f;
    }
    __syncthreads();
#pragma unroll
    for (int i = 0; i < 4; ++i) {
        int n = n0 + ty + i * 8;     // out row
        out[(size_t)n * K + k0 + tx] = f2b(tile[tx][ty + i * 8]);
    }
}

// ------ bf16 strided transpose, vectorized 16B both sides -------------------
__global__ __launch_bounds__(256) void transpose_b16(const u16* __restrict__ in,
                                                     u16* __restrict__ out,
                                                     int istride, int ioff) {
    __shared__ u16 tile[64][72];
    const int b = blockIdx.z;
    const int t0 = blockIdx.y * 64, c0 = blockIdx.x * 64;
    const int tid = threadIdx.x;
    const int rr = tid >> 3;        // 0..31
    const int c8 = tid & 7;         // 16B chunk within 64
#pragma unroll
    for (int p = 0; p < 2; ++p) {
        const int row = p * 32 + rr;
        *(uint4*)&tile[row][c8 * 8] =
            *(const uint4*)(in + (size_t)(b * T_ + t0 + row) * istride + ioff + c0 + c8 * 8);
    }
    __syncthreads();
#pragma unroll
    for (int p = 0; p < 2; ++p) {
        const int c = p * 32 + rr;
        u16 tmp[8];
#pragma unroll
        for (int j = 0; j < 8; ++j) tmp[j] = tile[c8 * 8 + j][c];
        *(uint4*)(out + ((size_t)b * 2048 + c0 + c) * 2048 + t0 + c8 * 8) = *(uint4*)tmp;
    }
}

// ---------------- bf16 GEMM:  C(MxN) = A(MxK) @ B(KxN), Bt given as NxK ------
template <int OUT_BF16>
__global__ __launch_bounds__(256) void gemm_tn(const u16* __restrict__ A,
                                               const u16* __restrict__ Bt,
                                               void* __restrict__ Cv,
                                               int N, int K) {
    __shared__ __attribute__((aligned(16))) u16 lA[128 * 32];
    __shared__ __attribute__((aligned(16))) u16 lB[128 * 32];
    const int m0 = blockIdx.y * 128, n0 = blockIdx.x * 128;
    const int tid = threadIdx.x, wave = tid >> 6, lane = tid & 63;
    const int wm = (wave >> 1) * 64, wn = (wave & 1) * 64;
    const int r = lane & 15, kq = lane >> 4;

    f32x4 acc[4][4];
#pragma unroll
    for (int i = 0; i < 4; ++i)
#pragma unroll
        for (int j = 0; j < 4; ++j) acc[i][j] = (f32x4){0.f, 0.f, 0.f, 0.f};

    for (int kk = 0; kk < K; kk += 32) {
#pragma unroll
        for (int p = 0; p < 2; ++p) {
            const int c = p * 256 + wave * 64 + lane;          // 16B chunk id
            const u16* ga = A  + (size_t)(m0 + (c >> 2)) * K + kk + (c & 3) * 8;
            const u16* gb = Bt + (size_t)(n0 + (c >> 2)) * K + kk + (c & 3) * 8;
            u16* la = lA + (size_t)(p * 256 + wave * 64) * 8;  // wave-uniform base
            u16* lb = lB + (size_t)(p * 256 + wave * 64) * 8;
            __builtin_amdgcn_global_load_lds(
                (const __attribute__((address_space(1))) uint32_t*)(uintptr_t)ga,
                (__attribute__((address_space(3))) uint32_t*)(uintptr_t)la, 16, 0, 0);
            __builtin_amdgcn_global_load_lds(
                (const __attribute__((address_space(1))) uint32_t*)(uintptr_t)gb,
                (__attribute__((address_space(3))) uint32_t*)(uintptr_t)lb, 16, 0, 0);
        }
        __syncthreads();
        short8 av[4], bv[4];
#pragma unroll
        for (int mi = 0; mi < 4; ++mi)
            av[mi] = *(const short8*)&lA[(wm + mi * 16 + r) * 32 + kq * 8];
#pragma unroll
        for (int ni = 0; ni < 4; ++ni)
            bv[ni] = *(const short8*)&lB[(wn + ni * 16 + r) * 32 + kq * 8];
#pragma unroll
        for (int mi = 0; mi < 4; ++mi)
#pragma unroll
            for (int ni = 0; ni < 4; ++ni)
                acc[mi][ni] = __builtin_amdgcn_mfma_f32_16x16x32_bf16(
                    av[mi], bv[ni], acc[mi][ni], 0, 0, 0);
        __syncthreads();
    }
    const int r4 = (lane >> 4) * 4, cc = lane & 15;
#pragma unroll
    for (int mi = 0; mi < 4; ++mi)
#pragma unroll
        for (int ni = 0; ni < 4; ++ni)
#pragma unroll
            for (int i = 0; i < 4; ++i) {
                const int row = m0 + wm + mi * 16 + r4 + i;
                const int col = n0 + wn + ni * 16 + cc;
                const float v = acc[mi][ni][i];
                if (OUT_BF16) ((u16*)Cv)[(size_t)row * N + col] = f2b(v);
                else          ((float*)Cv)[(size_t)row * N + col] = v;
            }
}

// ---- fused per-row ops on P1: rmsnorm(q), rmsnorm(kv), rope_k — one launch --
__global__ __launch_bounds__(256) void normrope_k(const u16* __restrict__ P1,
                                                  const float* __restrict__ qnw,
                                                  const float* __restrict__ kvnw,
                                                  u16* __restrict__ cQb,
                                                  u16* __restrict__ cKVb,
                                                  u16* __restrict__ kRb) {
    const int row = blockIdx.x;
    const int which = blockIdx.y;
    if (which < 2) {
        const int N = which ? 512 : 1024;
        const int off = which ? 1024 : 0;
        const float* w = which ? kvnw : qnw;
        u16* outp = which ? cKVb : cQb;
        const u16* src = P1 + (size_t)row * 1664 + off;
        const int j = threadIdx.x * 4;
        float v[4] = {0.f, 0.f, 0.f, 0.f};
        if (j < N) {
            ushort4 u = *(const ushort4*)(src + j);
            v[0] = b2f(u.x); v[1] = b2f(u.y); v[2] = b2f(u.z); v[3] = b2f(u.w);
        }
        float ss = v[0]*v[0] + v[1]*v[1] + v[2]*v[2] + v[3]*v[3];
#pragma unroll
        for (int offc = 32; offc; offc >>= 1) ss += __shfl_down(ss, offc);
        __shared__ float red[4];
        const int wave = threadIdx.x >> 6, lane = threadIdx.x & 63;
        if (lane == 0) red[wave] = ss;
        __syncthreads();
        const float tot = red[0] + red[1] + red[2] + red[3];
        const float sc = rsqrtf(tot / (float)N + 1e-6f);
        if (j < N) {
            ushort4 o;
            o.x = f2b(v[0] * sc * w[j]);
            o.y = f2b(v[1] * sc * w[j + 1]);
            o.z = f2b(v[2] * sc * w[j + 2]);
            o.w = f2b(v[3] * sc * w[j + 3]);
            *(ushort4*)(outp + (size_t)row * N + j) = o;
        }
    } else {
        const int j = threadIdx.x;               // only 0..63 active
        if (j < 64) {
            const int t = row & (T_ - 1);
            const int i = j & 31;
            const float invf = __expf(-LN_BASE_ * (float)(2 * i) * (1.0f / 64.0f));
            const float ang = (float)t * invf;
            const float c = cosf(ang), s = sinf(ang);
            const u16* src = P1 + (size_t)row * 1664 + 1536;
            const float v = b2f(src[j]);
            const float rot = (j < 32) ? -b2f(src[j + 32]) : b2f(src[j - 32]);
            kRb[(size_t)row * 64 + j] = f2b(v * c + rot * s);
        }
    }
}

// -------- RoPE for q, vectorized 8xu16 (chunk stays inside one half) --------
__global__ __launch_bounds__(256) void rope_q_k(const u16* __restrict__ in,
                                                u16* __restrict__ out,
                                                int stride, int off) {
    const int row = blockIdx.x * 2 + (threadIdx.x >> 7);   // 2 rows per block
    const int t = row & (T_ - 1);
    const int e0 = (threadIdx.x & 127) * 8;                // 0..1016
    const u16* src = in + (size_t)row * stride + off;
    const int j0 = e0 & 63;
    const ushort4* pv = (const ushort4*)(src + e0);
    const ushort4* pr = (const ushort4*)(src + (j0 < 32 ? e0 + 32 : e0 - 32));
    const float sgn = (j0 < 32) ? -1.f : 1.f;
    ushort4 v01 = pv[0], v23 = pv[1];
    ushort4 r01 = pr[0], r23 = pr[1];
    const u16 vv[8] = {v01.x, v01.y, v01.z, v01.w, v23.x, v23.y, v23.z, v23.w};
    const u16 rr[8] = {r01.x, r01.y, r01.z, r01.w, r23.x, r23.y, r23.z, r23.w};
    u16 o[8];
#pragma unroll
    for (int k = 0; k < 8; ++k) {
        const int i = (j0 + k) & 31;
        const float invf = __expf(-LN_BASE_ * (float)(2 * i) * (1.0f / 64.0f));
        const float ang = (float)t * invf;
        o[k] = f2b(b2f(vv[k]) * cosf(ang) + sgn * b2f(rr[k]) * sinf(ang));
    }
    *(uint4*)(out + (size_t)row * 1024 + e0) = *(uint4*)o;
}

// ---------------- MFMA flash attention (causal, d=192, dv=128) --------------
// 512 threads = 8 waves = 4 row-groups (32 q each) x 2 col-groups.
// S-phase: wave (rg,cg) computes 32q x 32k (kf reads halved).
// PV-phase: wave (rg,cg) computes 32q x 64dv-half over all 64 k (vf halved).
// P shared cross-wave per rg (barrier between write and read). No-max softmax:
// L is additive, each wave keeps k-half partials, merged once at epilogue.
#define ABQ  128
#define ABK  64
#define KSTR 200   // sK row stride u16
#define VSTR 72    // sV row stride u16
#define PSTR 72    // sP row stride u16
#define QSTRIDE 3072   // P2 row stride (qC cols 0..2047)
#define KSTRIDE 4096   // P3 row stride (kC cols 0..2047)

__global__ __launch_bounds__(512, 4) void attn_mfma_k(
    const u16* __restrict__ qC, const u16* __restrict__ qR,
    const u16* __restrict__ kC, const u16* __restrict__ kR,
    const u16* __restrict__ Vt, u16* __restrict__ outp)
{
    __shared__ __attribute__((aligned(16))) u16 sK[64 * KSTR];    // 25.6 KB
    __shared__ __attribute__((aligned(16))) u16 sV[128 * VSTR];   // 18.4 KB
    __shared__ __attribute__((aligned(16))) u16 sP[4 * 32 * PSTR];// 18.4 KB
    __shared__ float sL2[4][2][32];                               // 1 KB

    const int h = blockIdx.y, b = blockIdx.z;
    const int qb = b ? (15 - blockIdx.x) : blockIdx.x;   // causal balance
    const int q0 = qb * ABQ;
    const int tid = threadIdx.x, wave = tid >> 6, lane = tid & 63;
    const int rg = wave >> 1, cg = wave & 1;
    const int r = lane & 15, kq = lane >> 4, r4 = kq * 4;
    const int wq = rg * 32;

    // Q fragments (A-layout) in registers: [mt][kc], k = kc*32 + kq*8 + j
    short8 qf[2][6];
#pragma unroll
    for (int mt = 0; mt < 2; ++mt) {
        const int t = q0 + wq + mt * 16 + r;
        const u16* qcrow = qC + (size_t)(b * T_ + t) * QSTRIDE + h * 128 + kq * 8;
        const u16* qrrow = qR + (size_t)(b * T_ + t) * 1024 + h * 64 + kq * 8;
#pragma unroll
        for (int kc = 0; kc < 4; ++kc) qf[mt][kc] = *(const short8*)(qcrow + kc * 32);
#pragma unroll
        for (int kc = 0; kc < 2; ++kc) qf[mt][4 + kc] = *(const short8*)(qrrow + kc * 32);
    }

    f32x4 Oa[2][4];   // 32 q-rows x 64-dv half (nt2 = 0..3)
#pragma unroll
    for (int mt = 0; mt < 2; ++mt)
#pragma unroll
        for (int nt = 0; nt < 4; ++nt) Oa[mt][nt] = (f32x4){0.f, 0.f, 0.f, 0.f};
    float Lrow[2][4] = {{0.f,0.f,0.f,0.f},{0.f,0.f,0.f,0.f}};   // k-half partial

    u16* myP = sP + rg * 32 * PSTR;

    const int nkt = 2 * qb + 2;
    for (int kt = 0; kt < nkt; ++kt) {
        const int k0 = kt * ABK;
        // ---- stage K tile: 25 chunks of 1KB over 8 waves
        for (int i = wave; i < 25; i += 8) {
            const int s = i * 64 + lane;
            const int rr = s / 25;
            int cc = s - rr * 25;
            if (cc > 23) cc = 0;                       // pad slot: harmless dup
            const int t = k0 + rr;
            const u16* src = (cc < 16)
                ? kC + (size_t)(b * T_ + t) * KSTRIDE + h * 128 + cc * 8
                : kR + (size_t)(b * T_ + t) * 64 + (cc - 16) * 8;
            __builtin_amdgcn_global_load_lds(
                (const __attribute__((address_space(1))) uint32_t*)(uintptr_t)src,
                (__attribute__((address_space(3))) uint32_t*)(uintptr_t)(sK + i * 512),
                16, 0, 0);
        }
        // ---- stage V^T tile: 18 chunks
        for (int i = wave; i < 18; i += 8) {
            const int s = i * 64 + lane;
            const int rr = s / 9;
            int cc = s - rr * 9;
            if (cc > 7) cc = 0;                        // pad slot
            const u16* src = Vt + ((size_t)(b * H_ + h) * 128 + rr) * T_ + k0 + cc * 8;
            __builtin_amdgcn_global_load_lds(
                (const __attribute__((address_space(1))) uint32_t*)(uintptr_t)src,
                (__attribute__((address_space(3))) uint32_t*)(uintptr_t)(sV + i * 512),
                16, 0, 0);
        }
        __syncthreads();

        // ---- S = Q K^T for this wave's 32k half (24 MFMA/wave)
        f32x4 Sa[2][2];
#pragma unroll
        for (int mt = 0; mt < 2; ++mt)
#pragma unroll
            for (int nt = 0; nt < 2; ++nt) Sa[mt][nt] = (f32x4){0.f, 0.f, 0.f, 0.f};
#pragma unroll
        for (int kc = 0; kc < 6; ++kc) {
            short8 kf[2];
#pragma unroll
            for (int nt = 0; nt < 2; ++nt)
                kf[nt] = *(const short8*)&sK[((cg * 2 + nt) * 16 + r) * KSTR + (kc * 4 + kq) * 8];
#pragma unroll
            for (int mt = 0; mt < 2; ++mt)
#pragma unroll
                for (int nt = 0; nt < 2; ++nt)
                    Sa[mt][nt] = __builtin_amdgcn_mfma_f32_16x16x32_bf16(
                        qf[mt][kc], kf[nt], Sa[mt][nt], 0, 0, 0);
        }

        // ---- no-max softmax on this k-half; P -> shared LDS
        if (kt < nkt - 2) {
#pragma unroll
            for (int mt = 0; mt < 2; ++mt)
#pragma unroll
                for (int i = 0; i < 4; ++i) {
                    float p[2];
#pragma unroll
                    for (int nt = 0; nt < 2; ++nt) p[nt] = exp2f(Sa[mt][nt][i] * SC2_);
                    Lrow[mt][i] += p[0] + p[1];
#pragma unroll
                    for (int nt = 0; nt < 2; ++nt)
                        myP[(mt * 16 + r4 + i) * PSTR + (cg * 2 + nt) * 16 + r] = f2b_fast(p[nt]);
                }
        } else {
#pragma unroll
            for (int mt = 0; mt < 2; ++mt)
#pragma unroll
                for (int i = 0; i < 4; ++i) {
                    const int grow = q0 + wq + mt * 16 + r4 + i;
                    float p[2];
#pragma unroll
                    for (int nt = 0; nt < 2; ++nt) {
                        float pv = exp2f(Sa[mt][nt][i] * SC2_);
                        p[nt] = (k0 + (cg * 2 + nt) * 16 + r > grow) ? 0.f : pv;
                    }
                    Lrow[mt][i] += p[0] + p[1];
#pragma unroll
                    for (int nt = 0; nt < 2; ++nt)
                        myP[(mt * 16 + r4 + i) * PSTR + (cg * 2 + nt) * 16 + r] = f2b_fast(p[nt]);
                }
        }
        __syncthreads();   // P halves visible to both cg waves of each rg

        // ---- O += P V for this wave's 64-dv half (16 MFMA/wave)
#pragma unroll
        for (int kc2 = 0; kc2 < 2; ++kc2) {
            short8 pf[2];
#pragma unroll
            for (int mt = 0; mt < 2; ++mt)
                pf[mt] = *(const short8*)&myP[(mt * 16 + r) * PSTR + (kc2 * 4 + kq) * 8];
#pragma unroll
            for (int nt = 0; nt < 4; ++nt) {
                const short8 vf =
                    *(const short8*)&sV[((cg * 4 + nt) * 16 + r) * VSTR + (kc2 * 4 + kq) * 8];
#pragma unroll
                for (int mt = 0; mt < 2; ++mt)
                    Oa[mt][nt] = __builtin_amdgcn_mfma_f32_16x16x32_bf16(
                        pf[mt], vf, Oa[mt][nt], 0, 0, 0);
            }
        }
        __syncthreads();   // sK/sV/sP free for next tile
    }

    // ---- epilogue: merge L halves across cg, O /= L, store
    float Lp[2][4];
#pragma unroll
    for (int mt = 0; mt < 2; ++mt)
#pragma unroll
        for (int i = 0; i < 4; ++i) {
            float L = Lrow[mt][i];
            L += __shfl_xor(L, 1);
            L += __shfl_xor(L, 2);
            L += __shfl_xor(L, 4);
            L += __shfl_xor(L, 8);
            Lp[mt][i] = L;
        }
    if (r == 0) {
#pragma unroll
        for (int mt = 0; mt < 2; ++mt)
#pragma unroll
            for (int i = 0; i < 4; ++i)
                sL2[rg][cg][mt * 16 + r4 + i] = Lp[mt][i];
    }
    __syncthreads();
#pragma unroll
    for (int mt = 0; mt < 2; ++mt)
#pragma unroll
        for (int i = 0; i < 4; ++i) {
            const int lrow = mt * 16 + r4 + i;
            const float inv = 1.0f / (sL2[rg][0][lrow] + sL2[rg][1][lrow]);
            const int t = q0 + wq + lrow;
            u16* orow = outp + (size_t)(b * T_ + t) * 2048 + h * 128 + cg * 64;
#pragma unroll
            for (int nt = 0; nt < 4; ++nt)
                orow[nt * 16 + r] = f2b(Oa[mt][nt][i] * inv);
        }
}

// ---------------- host side -------------------------------------------------
// Workspace plan: 139.46 MB (proven safe; 153 MB OOB'd in round 4).
// U1 time-shared: P1 (phase 1) then attn_out (phase 3). Vt reuses xb.
extern "C" void kernel_launch(void* const* d_in, const int* in_sizes, int n_in,
                              void* d_out, int out_size, void* d_ws, size_t ws_size,
                              hipStream_t stream) {
    (void)in_sizes; (void)n_in; (void)out_size; (void)ws_size;
    const float* x     = (const float*)d_in[0];
    const float* W_DQ  = (const float*)d_in[1];
    const float* W_UQ  = (const float*)d_in[2];
    const float* W_QR  = (const float*)d_in[3];
    const float* W_DKV = (const float*)d_in[4];
    const float* W_UK  = (const float*)d_in[5];
    const float* W_UV  = (const float*)d_in[6];
    const float* W_KR  = (const float*)d_in[7];
    const float* W_O   = (const float*)d_in[8];
    const float* qnw   = (const float*)d_in[9];
    const float* kvnw  = (const float*)d_in[10];
    float* out = (float*)d_out;   // fp32 output per reference dtype

    char* base = (char*)d_ws;
    size_t o = 0;
    auto alloc = [&](size_t bytes) {
        char* r = base + o;
        o += (bytes + 255) & ~(size_t)255;
        return r;
    };
    u16* WT1  = (u16*)alloc((size_t)1664 * 2048 * 2);
    u16* WT2  = (u16*)alloc((size_t)3072 * 1024 * 2);
    u16* WT3  = (u16*)alloc((size_t)4096 * 512 * 2);
    u16* WT_O = (u16*)alloc((size_t)2048 * 2048 * 2);
    u16* xb   = (u16*)alloc((size_t)M_ * 2048 * 2);    // x bf16; later Vt
    u16* U1   = (u16*)alloc((size_t)M_ * 2048 * 2);    // P1 then attn_out
    u16* P2   = (u16*)alloc((size_t)M_ * 3072 * 2);    // [qC | qR_raw]
    u16* P3   = (u16*)alloc((size_t)M_ * 4096 * 2);    // [kC | vC]
    u16* cQb  = (u16*)alloc((size_t)M_ * 1024 * 2);
    u16* cKVb = (u16*)alloc((size_t)M_ * 512 * 2);
    u16* qRb  = (u16*)alloc((size_t)M_ * 1024 * 2);
    u16* kRb  = (u16*)alloc((size_t)M_ * 64 * 2);
    u16* P1       = U1;
    u16* attn_out = U1;
    u16* Vt       = xb;

    // ---- one fused transpose launch for all 8 weights
    TPack tp;
    const float* srcs[8] = {W_DQ, W_DKV, W_KR, W_UQ, W_QR, W_UK, W_UV, W_O};
    u16* dsts[8] = {WT1, WT1 + (size_t)1024*2048, WT1 + (size_t)1536*2048,
                    WT2, WT2 + (size_t)2048*1024,
                    WT3, WT3 + (size_t)2048*512, WT_O};
    const int Ks[8]   = {2048, 2048, 2048, 1024, 1024, 512, 512, 2048};
    const int Ns[8]   = {1024,  512,   64, 2048, 1024, 2048, 2048, 2048};
    const int ntxs[8] = {  32,   16,    4,   64,   32,   64,   64,   64};
    int cum = 0;
    for (int i = 0; i < 8; ++i) {
        tp.src[i] = srcs[i]; tp.dst[i] = dsts[i];
        tp.K[i] = Ks[i]; tp.N[i] = Ns[i]; tp.ntx[i] = ntxs[i];
        tp.start[i] = cum;
        cum += ntxs[i] * (Ks[i] / 32);
    }
    tp.start[8] = cum;   // 12544 tiles

    const dim3 tb(32, 8);
    transpose_all<<<cum, tb, 0, stream>>>(tp);

    cast_f2b_k<<<(M_ * D_) / 1024, 256, 0, stream>>>(x, xb);

    // proj1: x @ [W_DQ | W_DKV | W_KR]  -> P1 (M x 1664)
    gemm_tn<1><<<dim3(1664/128, M_/128), 256, 0, stream>>>(xb, WT1, (void*)P1, 1664, 2048);

    // fused rmsnorm(q) + rmsnorm(kv) + rope_k
    normrope_k<<<dim3(M_, 3), 256, 0, stream>>>(P1, qnw, kvnw, cQb, cKVb, kRb);

    // proj2a: cQ @ [W_UQ | W_QR] -> P2;  proj2b: cKV @ [W_UK | W_UV] -> P3
    gemm_tn<1><<<dim3(3072/128, M_/128), 256, 0, stream>>>(cQb,  WT2, (void*)P2, 3072, 1024);
    gemm_tn<1><<<dim3(4096/128, M_/128), 256, 0, stream>>>(cKVb, WT3, (void*)P3, 4096, 512);

    rope_q_k<<<M_/2, 256, 0, stream>>>(P2, qRb, 3072, 2048);

    // V^T for MFMA B-operand: P3 cols 2048..4095 -> Vt (b, h*128+dv, T)
    transpose_b16<<<dim3(32, 32, B_), 256, 0, stream>>>(P3, Vt, 4096, 2048);

    // attn writes attn_out (=U1; P1 dead from here)
    attn_mfma_k<<<dim3(T_/ABQ, H_, B_), 512, 0, stream>>>(P2, qRb, P3, kRb, Vt, attn_out);

    // output projection -> d_out (fp32)
    gemm_tn<0><<<dim3(2048/128, M_/128), 256, 0, stream>>>(attn_out, WT_O, (void*)out, 2048, 2048);
}

// Round 9
// 469.825 us; speedup vs baseline: 1.0303x; 1.0303x over previous
//
#include <hip/hip_runtime.h>
#include <cstdint>
#include <cstddef>

// ---------------- problem constants ----------------
#define B_   2
#define T_   2048
#define D_   2048
#define H_   16
#define DH_  128
#define DQ_  1024
#define DKV_ 512
#define DR_  64
#define M_   4096            // B_*T_
#define SCALE_ 0.07216878364870323f   // 1/sqrt(DH_+DR_)
#define SC2_   0.10412808709930322f   // SCALE_ * log2(e)
#define LN_BASE_ 13.122363377404328f  // ln(500000)

typedef unsigned short u16;
typedef __attribute__((ext_vector_type(8))) short short8;   // 8 bf16 (4 VGPRs)
typedef __attribute__((ext_vector_type(4))) float f32x4;    // 4 fp32 acc

__device__ __forceinline__ float b2f(u16 u) { return __uint_as_float(((uint32_t)u) << 16); }
__device__ __forceinline__ u16 f2b(float f) {            // RNE
    uint32_t x = __float_as_uint(f);
    return (u16)((x + 0x7fffu + ((x >> 16) & 1u)) >> 16);
}
__device__ __forceinline__ u16 f2b_fast(float f) {       // round-up-ties, 2 ops
    return (u16)((__float_as_uint(f) + 0x8000u) >> 16);
}

// ---------------- fp32 -> bf16 elementwise cast -----------------------------
__global__ __launch_bounds__(256) void cast_f2b_k(const float* __restrict__ in,
                                                  u16* __restrict__ out) {
    const int i = (blockIdx.x * 256 + threadIdx.x) * 4;
    const float4 v = *(const float4*)(in + i);
    ushort4 o;
    o.x = f2b(v.x); o.y = f2b(v.y); o.z = f2b(v.z); o.w = f2b(v.w);
    *(ushort4*)(out + i) = o;
}

// ---------- fused weight transpose+cast: 8 weights in one launch ------------
struct TPack {
    const float* src[8];
    u16*         dst[8];
    int K[8];      // src rows
    int N[8];      // src cols (real)
    int ntx[8];    // tiles along out-row dim (covers padded N)
    int start[9];  // cumulative tile offsets
};

__global__ __launch_bounds__(256) void transpose_all(TPack p) {
    __shared__ float tile[32][33];
    const int bid = blockIdx.x;
    int w = 0;
#pragma unroll
    for (int i = 1; i < 8; ++i) if (bid >= p.start[i]) w = i;
    const int lt = bid - p.start[w];
    const int bx = lt % p.ntx[w], by = lt / p.ntx[w];
    const float* in = p.src[w];
    u16* out = p.dst[w];
    const int K = p.K[w], N = p.N[w];
    const int k0 = by * 32, n0 = bx * 32;
    const int tx = threadIdx.x, ty = threadIdx.y;  // (32,8)
#pragma unroll
    for (int i = 0; i < 4; ++i) {
        int k = k0 + ty + i * 8;
        int n = n0 + tx;
        tile[ty + i * 8][tx] = (n < N) ? in[(size_t)k * N + n] : 0.f;
    }
    __syncthreads();
#pragma unroll
    for (int i = 0; i < 4; ++i) {
        int n = n0 + ty + i * 8;     // out row
        out[(size_t)n * K + k0 + tx] = f2b(tile[tx][ty + i * 8]);
    }
}

// ------ bf16 strided transpose, vectorized 16B both sides -------------------
__global__ __launch_bounds__(256) void transpose_b16(const u16* __restrict__ in,
                                                     u16* __restrict__ out,
                                                     int istride, int ioff) {
    __shared__ u16 tile[64][72];
    const int b = blockIdx.z;
    const int t0 = blockIdx.y * 64, c0 = blockIdx.x * 64;
    const int tid = threadIdx.x;
    const int rr = tid >> 3;        // 0..31
    const int c8 = tid & 7;         // 16B chunk within 64
#pragma unroll
    for (int p = 0; p < 2; ++p) {
        const int row = p * 32 + rr;
        *(uint4*)&tile[row][c8 * 8] =
            *(const uint4*)(in + (size_t)(b * T_ + t0 + row) * istride + ioff + c0 + c8 * 8);
    }
    __syncthreads();
#pragma unroll
    for (int p = 0; p < 2; ++p) {
        const int c = p * 32 + rr;
        u16 tmp[8];
#pragma unroll
        for (int j = 0; j < 8; ++j) tmp[j] = tile[c8 * 8 + j][c];
        *(uint4*)(out + ((size_t)b * 2048 + c0 + c) * 2048 + t0 + c8 * 8) = *(uint4*)tmp;
    }
}

// ---------------- bf16 GEMM:  C(MxN) = A(MxK) @ B(KxN), Bt given as NxK ------
template <int OUT_BF16>
__global__ __launch_bounds__(256) void gemm_tn(const u16* __restrict__ A,
                                               const u16* __restrict__ Bt,
                                               void* __restrict__ Cv,
                                               int N, int K) {
    __shared__ __attribute__((aligned(16))) u16 lA[128 * 32];
    __shared__ __attribute__((aligned(16))) u16 lB[128 * 32];
    const int m0 = blockIdx.y * 128, n0 = blockIdx.x * 128;
    const int tid = threadIdx.x, wave = tid >> 6, lane = tid & 63;
    const int wm = (wave >> 1) * 64, wn = (wave & 1) * 64;
    const int r = lane & 15, kq = lane >> 4;

    f32x4 acc[4][4];
#pragma unroll
    for (int i = 0; i < 4; ++i)
#pragma unroll
        for (int j = 0; j < 4; ++j) acc[i][j] = (f32x4){0.f, 0.f, 0.f, 0.f};

    for (int kk = 0; kk < K; kk += 32) {
#pragma unroll
        for (int p = 0; p < 2; ++p) {
            const int c = p * 256 + wave * 64 + lane;          // 16B chunk id
            const u16* ga = A  + (size_t)(m0 + (c >> 2)) * K + kk + (c & 3) * 8;
            const u16* gb = Bt + (size_t)(n0 + (c >> 2)) * K + kk + (c & 3) * 8;
            u16* la = lA + (size_t)(p * 256 + wave * 64) * 8;  // wave-uniform base
            u16* lb = lB + (size_t)(p * 256 + wave * 64) * 8;
            __builtin_amdgcn_global_load_lds(
                (const __attribute__((address_space(1))) uint32_t*)(uintptr_t)ga,
                (__attribute__((address_space(3))) uint32_t*)(uintptr_t)la, 16, 0, 0);
            __builtin_amdgcn_global_load_lds(
                (const __attribute__((address_space(1))) uint32_t*)(uintptr_t)gb,
                (__attribute__((address_space(3))) uint32_t*)(uintptr_t)lb, 16, 0, 0);
        }
        __syncthreads();
        short8 av[4], bv[4];
#pragma unroll
        for (int mi = 0; mi < 4; ++mi)
            av[mi] = *(const short8*)&lA[(wm + mi * 16 + r) * 32 + kq * 8];
#pragma unroll
        for (int ni = 0; ni < 4; ++ni)
            bv[ni] = *(const short8*)&lB[(wn + ni * 16 + r) * 32 + kq * 8];
#pragma unroll
        for (int mi = 0; mi < 4; ++mi)
#pragma unroll
            for (int ni = 0; ni < 4; ++ni)
                acc[mi][ni] = __builtin_amdgcn_mfma_f32_16x16x32_bf16(
                    av[mi], bv[ni], acc[mi][ni], 0, 0, 0);
        __syncthreads();
    }
    const int r4 = (lane >> 4) * 4, cc = lane & 15;
#pragma unroll
    for (int mi = 0; mi < 4; ++mi)
#pragma unroll
        for (int ni = 0; ni < 4; ++ni)
#pragma unroll
            for (int i = 0; i < 4; ++i) {
                const int row = m0 + wm + mi * 16 + r4 + i;
                const int col = n0 + wn + ni * 16 + cc;
                const float v = acc[mi][ni][i];
                if (OUT_BF16) ((u16*)Cv)[(size_t)row * N + col] = f2b(v);
                else          ((float*)Cv)[(size_t)row * N + col] = v;
            }
}

// ---- fused per-row ops on P1: rmsnorm(q), rmsnorm(kv), rope_k — one launch --
__global__ __launch_bounds__(256) void normrope_k(const u16* __restrict__ P1,
                                                  const float* __restrict__ qnw,
                                                  const float* __restrict__ kvnw,
                                                  u16* __restrict__ cQb,
                                                  u16* __restrict__ cKVb,
                                                  u16* __restrict__ kRb) {
    const int row = blockIdx.x;
    const int which = blockIdx.y;
    if (which < 2) {
        const int N = which ? 512 : 1024;
        const int off = which ? 1024 : 0;
        const float* w = which ? kvnw : qnw;
        u16* outp = which ? cKVb : cQb;
        const u16* src = P1 + (size_t)row * 1664 + off;
        const int j = threadIdx.x * 4;
        float v[4] = {0.f, 0.f, 0.f, 0.f};
        if (j < N) {
            ushort4 u = *(const ushort4*)(src + j);
            v[0] = b2f(u.x); v[1] = b2f(u.y); v[2] = b2f(u.z); v[3] = b2f(u.w);
        }
        float ss = v[0]*v[0] + v[1]*v[1] + v[2]*v[2] + v[3]*v[3];
#pragma unroll
        for (int offc = 32; offc; offc >>= 1) ss += __shfl_down(ss, offc);
        __shared__ float red[4];
        const int wave = threadIdx.x >> 6, lane = threadIdx.x & 63;
        if (lane == 0) red[wave] = ss;
        __syncthreads();
        const float tot = red[0] + red[1] + red[2] + red[3];
        const float sc = rsqrtf(tot / (float)N + 1e-6f);
        if (j < N) {
            ushort4 o;
            o.x = f2b(v[0] * sc * w[j]);
            o.y = f2b(v[1] * sc * w[j + 1]);
            o.z = f2b(v[2] * sc * w[j + 2]);
            o.w = f2b(v[3] * sc * w[j + 3]);
            *(ushort4*)(outp + (size_t)row * N + j) = o;
        }
    } else {
        const int j = threadIdx.x;               // only 0..63 active
        if (j < 64) {
            const int t = row & (T_ - 1);
            const int i = j & 31;
            const float invf = __expf(-LN_BASE_ * (float)(2 * i) * (1.0f / 64.0f));
            const float ang = (float)t * invf;
            const float c = cosf(ang), s = sinf(ang);
            const u16* src = P1 + (size_t)row * 1664 + 1536;
            const float v = b2f(src[j]);
            const float rot = (j < 32) ? -b2f(src[j + 32]) : b2f(src[j - 32]);
            kRb[(size_t)row * 64 + j] = f2b(v * c + rot * s);
        }
    }
}

// -------- RoPE for q, vectorized 8xu16 (chunk stays inside one half) --------
__global__ __launch_bounds__(256) void rope_q_k(const u16* __restrict__ in,
                                                u16* __restrict__ out,
                                                int stride, int off) {
    const int row = blockIdx.x * 2 + (threadIdx.x >> 7);   // 2 rows per block
    const int t = row & (T_ - 1);
    const int e0 = (threadIdx.x & 127) * 8;                // 0..1016
    const u16* src = in + (size_t)row * stride + off;
    const int j0 = e0 & 63;
    const ushort4* pv = (const ushort4*)(src + e0);
    const ushort4* pr = (const ushort4*)(src + (j0 < 32 ? e0 + 32 : e0 - 32));
    const float sgn = (j0 < 32) ? -1.f : 1.f;
    ushort4 v01 = pv[0], v23 = pv[1];
    ushort4 r01 = pr[0], r23 = pr[1];
    const u16 vv[8] = {v01.x, v01.y, v01.z, v01.w, v23.x, v23.y, v23.z, v23.w};
    const u16 rr[8] = {r01.x, r01.y, r01.z, r01.w, r23.x, r23.y, r23.z, r23.w};
    u16 o[8];
#pragma unroll
    for (int k = 0; k < 8; ++k) {
        const int i = (j0 + k) & 31;
        const float invf = __expf(-LN_BASE_ * (float)(2 * i) * (1.0f / 64.0f));
        const float ang = (float)t * invf;
        o[k] = f2b(b2f(vv[k]) * cosf(ang) + sgn * b2f(rr[k]) * sinf(ang));
    }
    *(uint4*)(out + (size_t)row * 1024 + e0) = *(uint4*)o;
}

// ---------------- MFMA flash attention (causal, d=192, dv=128) --------------
// 512 threads = 8 waves = 4 row-groups (32 q each) x 2 col-groups.
// S-phase: wave (rg,cg) computes 32q x 32k (kf reads halved).
// PV-phase: wave (rg,cg) computes 32q x 64dv-half over all 64 k (vf halved).
// P shared cross-wave per rg (barrier between write and read). No-max softmax:
// L additive; k-half partials merged once at epilogue.
// __launch_bounds__(512, 2): VGPR cap >=128 (R8's (512,4) resolved to a 64-VGPR
// cap -> ~100MB scratch spill traffic, WRITE_SIZE 16->61MB — the R8 regression).
#define ABQ  128
#define ABK  64
#define KSTR 200   // sK row stride u16
#define VSTR 72    // sV row stride u16
#define PSTR 72    // sP row stride u16
#define QSTRIDE 3072   // P2 row stride (qC cols 0..2047)
#define KSTRIDE 4096   // P3 row stride (kC cols 0..2047)

__global__ __launch_bounds__(512, 2) void attn_mfma_k(
    const u16* __restrict__ qC, const u16* __restrict__ qR,
    const u16* __restrict__ kC, const u16* __restrict__ kR,
    const u16* __restrict__ Vt, u16* __restrict__ outp)
{
    __shared__ __attribute__((aligned(16))) u16 sK[64 * KSTR];    // 25.6 KB
    __shared__ __attribute__((aligned(16))) u16 sV[128 * VSTR];   // 18.4 KB
    __shared__ __attribute__((aligned(16))) u16 sP[4 * 32 * PSTR];// 18.4 KB
    __shared__ float sL2[4][2][32];                               // 1 KB

    const int h = blockIdx.y, b = blockIdx.z;
    const int qb = b ? (15 - blockIdx.x) : blockIdx.x;   // causal balance
    const int q0 = qb * ABQ;
    const int tid = threadIdx.x, wave = tid >> 6, lane = tid & 63;
    const int rg = wave >> 1, cg = wave & 1;
    const int r = lane & 15, kq = lane >> 4, r4 = kq * 4;
    const int wq = rg * 32;

    // Q fragments (A-layout) in registers: [mt][kc], k = kc*32 + kq*8 + j
    short8 qf[2][6];
#pragma unroll
    for (int mt = 0; mt < 2; ++mt) {
        const int t = q0 + wq + mt * 16 + r;
        const u16* qcrow = qC + (size_t)(b * T_ + t) * QSTRIDE + h * 128 + kq * 8;
        const u16* qrrow = qR + (size_t)(b * T_ + t) * 1024 + h * 64 + kq * 8;
#pragma unroll
        for (int kc = 0; kc < 4; ++kc) qf[mt][kc] = *(const short8*)(qcrow + kc * 32);
#pragma unroll
        for (int kc = 0; kc < 2; ++kc) qf[mt][4 + kc] = *(const short8*)(qrrow + kc * 32);
    }

    f32x4 Oa[2][4];   // 32 q-rows x 64-dv half
#pragma unroll
    for (int mt = 0; mt < 2; ++mt)
#pragma unroll
        for (int nt = 0; nt < 4; ++nt) Oa[mt][nt] = (f32x4){0.f, 0.f, 0.f, 0.f};
    float Lrow[2][4] = {{0.f,0.f,0.f,0.f},{0.f,0.f,0.f,0.f}};   // k-half partial

    u16* myP = sP + rg * 32 * PSTR;

    const int nkt = 2 * qb + 2;
    for (int kt = 0; kt < nkt; ++kt) {
        const int k0 = kt * ABK;
        // ---- stage K tile: 25 chunks of 1KB over 8 waves
        for (int i = wave; i < 25; i += 8) {
            const int s = i * 64 + lane;
            const int rr = s / 25;
            int cc = s - rr * 25;
            if (cc > 23) cc = 0;                       // pad slot: harmless dup
            const int t = k0 + rr;
            const u16* src = (cc < 16)
                ? kC + (size_t)(b * T_ + t) * KSTRIDE + h * 128 + cc * 8
                : kR + (size_t)(b * T_ + t) * 64 + (cc - 16) * 8;
            __builtin_amdgcn_global_load_lds(
                (const __attribute__((address_space(1))) uint32_t*)(uintptr_t)src,
                (__attribute__((address_space(3))) uint32_t*)(uintptr_t)(sK + i * 512),
                16, 0, 0);
        }
        // ---- stage V^T tile: 18 chunks
        for (int i = wave; i < 18; i += 8) {
            const int s = i * 64 + lane;
            const int rr = s / 9;
            int cc = s - rr * 9;
            if (cc > 7) cc = 0;                        // pad slot
            const u16* src = Vt + ((size_t)(b * H_ + h) * 128 + rr) * T_ + k0 + cc * 8;
            __builtin_amdgcn_global_load_lds(
                (const __attribute__((address_space(1))) uint32_t*)(uintptr_t)src,
                (__attribute__((address_space(3))) uint32_t*)(uintptr_t)(sV + i * 512),
                16, 0, 0);
        }
        __syncthreads();

        // ---- S = Q K^T for this wave's 32k half (24 MFMA/wave)
        f32x4 Sa[2][2];
#pragma unroll
        for (int mt = 0; mt < 2; ++mt)
#pragma unroll
            for (int nt = 0; nt < 2; ++nt) Sa[mt][nt] = (f32x4){0.f, 0.f, 0.f, 0.f};
#pragma unroll
        for (int kc = 0; kc < 6; ++kc) {
            short8 kf[2];
#pragma unroll
            for (int nt = 0; nt < 2; ++nt)
                kf[nt] = *(const short8*)&sK[((cg * 2 + nt) * 16 + r) * KSTR + (kc * 4 + kq) * 8];
#pragma unroll
            for (int mt = 0; mt < 2; ++mt)
#pragma unroll
                for (int nt = 0; nt < 2; ++nt)
                    Sa[mt][nt] = __builtin_amdgcn_mfma_f32_16x16x32_bf16(
                        qf[mt][kc], kf[nt], Sa[mt][nt], 0, 0, 0);
        }

        // ---- no-max softmax on this k-half; P -> shared LDS
        if (kt < nkt - 2) {
#pragma unroll
            for (int mt = 0; mt < 2; ++mt)
#pragma unroll
                for (int i = 0; i < 4; ++i) {
                    float p[2];
#pragma unroll
                    for (int nt = 0; nt < 2; ++nt) p[nt] = exp2f(Sa[mt][nt][i] * SC2_);
                    Lrow[mt][i] += p[0] + p[1];
#pragma unroll
                    for (int nt = 0; nt < 2; ++nt)
                        myP[(mt * 16 + r4 + i) * PSTR + (cg * 2 + nt) * 16 + r] = f2b_fast(p[nt]);
                }
        } else {
#pragma unroll
            for (int mt = 0; mt < 2; ++mt)
#pragma unroll
                for (int i = 0; i < 4; ++i) {
                    const int grow = q0 + wq + mt * 16 + r4 + i;
                    float p[2];
#pragma unroll
                    for (int nt = 0; nt < 2; ++nt) {
                        float pv = exp2f(Sa[mt][nt][i] * SC2_);
                        p[nt] = (k0 + (cg * 2 + nt) * 16 + r > grow) ? 0.f : pv;
                    }
                    Lrow[mt][i] += p[0] + p[1];
#pragma unroll
                    for (int nt = 0; nt < 2; ++nt)
                        myP[(mt * 16 + r4 + i) * PSTR + (cg * 2 + nt) * 16 + r] = f2b_fast(p[nt]);
                }
        }
        __syncthreads();   // P halves visible to both cg waves of each rg

        // ---- O += P V for this wave's 64-dv half (16 MFMA/wave)
#pragma unroll
        for (int kc2 = 0; kc2 < 2; ++kc2) {
            short8 pf[2];
#pragma unroll
            for (int mt = 0; mt < 2; ++mt)
                pf[mt] = *(const short8*)&myP[(mt * 16 + r) * PSTR + (kc2 * 4 + kq) * 8];
#pragma unroll
            for (int nt = 0; nt < 4; ++nt) {
                const short8 vf =
                    *(const short8*)&sV[((cg * 4 + nt) * 16 + r) * VSTR + (kc2 * 4 + kq) * 8];
#pragma unroll
                for (int mt = 0; mt < 2; ++mt)
                    Oa[mt][nt] = __builtin_amdgcn_mfma_f32_16x16x32_bf16(
                        pf[mt], vf, Oa[mt][nt], 0, 0, 0);
            }
        }
        __syncthreads();   // sK/sV/sP free for next tile
    }

    // ---- epilogue: merge L halves across cg, O /= L, store
    float Lp[2][4];
#pragma unroll
    for (int mt = 0; mt < 2; ++mt)
#pragma unroll
        for (int i = 0; i < 4; ++i) {
            float L = Lrow[mt][i];
            L += __shfl_xor(L, 1);
            L += __shfl_xor(L, 2);
            L += __shfl_xor(L, 4);
            L += __shfl_xor(L, 8);
            Lp[mt][i] = L;
        }
    if (r == 0) {
#pragma unroll
        for (int mt = 0; mt < 2; ++mt)
#pragma unroll
            for (int i = 0; i < 4; ++i)
                sL2[rg][cg][mt * 16 + r4 + i] = Lp[mt][i];
    }
    __syncthreads();
#pragma unroll
    for (int mt = 0; mt < 2; ++mt)
#pragma unroll
        for (int i = 0; i < 4; ++i) {
            const int lrow = mt * 16 + r4 + i;
            const float inv = 1.0f / (sL2[rg][0][lrow] + sL2[rg][1][lrow]);
            const int t = q0 + wq + lrow;
            u16* orow = outp + (size_t)(b * T_ + t) * 2048 + h * 128 + cg * 64;
#pragma unroll
            for (int nt = 0; nt < 4; ++nt)
                orow[nt * 16 + r] = f2b(Oa[mt][nt][i] * inv);
        }
}

// ---------------- host side -------------------------------------------------
// Workspace plan: 139.46 MB (proven safe; 153 MB OOB'd in round 4).
// U1 time-shared: P1 (phase 1) then attn_out (phase 3). Vt reuses xb.
extern "C" void kernel_launch(void* const* d_in, const int* in_sizes, int n_in,
                              void* d_out, int out_size, void* d_ws, size_t ws_size,
                              hipStream_t stream) {
    (void)in_sizes; (void)n_in; (void)out_size; (void)ws_size;
    const float* x     = (const float*)d_in[0];
    const float* W_DQ  = (const float*)d_in[1];
    const float* W_UQ  = (const float*)d_in[2];
    const float* W_QR  = (const float*)d_in[3];
    const float* W_DKV = (const float*)d_in[4];
    const float* W_UK  = (const float*)d_in[5];
    const float* W_UV  = (const float*)d_in[6];
    const float* W_KR  = (const float*)d_in[7];
    const float* W_O   = (const float*)d_in[8];
    const float* qnw   = (const float*)d_in[9];
    const float* kvnw  = (const float*)d_in[10];
    float* out = (float*)d_out;   // fp32 output per reference dtype

    char* base = (char*)d_ws;
    size_t o = 0;
    auto alloc = [&](size_t bytes) {
        char* r = base + o;
        o += (bytes + 255) & ~(size_t)255;
        return r;
    };
    u16* WT1  = (u16*)alloc((size_t)1664 * 2048 * 2);
    u16* WT2  = (u16*)alloc((size_t)3072 * 1024 * 2);
    u16* WT3  = (u16*)alloc((size_t)4096 * 512 * 2);
    u16* WT_O = (u16*)alloc((size_t)2048 * 2048 * 2);
    u16* xb   = (u16*)alloc((size_t)M_ * 2048 * 2);    // x bf16; later Vt
    u16* U1   = (u16*)alloc((size_t)M_ * 2048 * 2);    // P1 then attn_out
    u16* P2   = (u16*)alloc((size_t)M_ * 3072 * 2);    // [qC | qR_raw]
    u16* P3   = (u16*)alloc((size_t)M_ * 4096 * 2);    // [kC | vC]
    u16* cQb  = (u16*)alloc((size_t)M_ * 1024 * 2);
    u16* cKVb = (u16*)alloc((size_t)M_ * 512 * 2);
    u16* qRb  = (u16*)alloc((size_t)M_ * 1024 * 2);
    u16* kRb  = (u16*)alloc((size_t)M_ * 64 * 2);
    u16* P1       = U1;
    u16* attn_out = U1;
    u16* Vt       = xb;

    // ---- one fused transpose launch for all 8 weights
    TPack tp;
    const float* srcs[8] = {W_DQ, W_DKV, W_KR, W_UQ, W_QR, W_UK, W_UV, W_O};
    u16* dsts[8] = {WT1, WT1 + (size_t)1024*2048, WT1 + (size_t)1536*2048,
                    WT2, WT2 + (size_t)2048*1024,
                    WT3, WT3 + (size_t)2048*512, WT_O};
    const int Ks[8]   = {2048, 2048, 2048, 1024, 1024, 512, 512, 2048};
    const int Ns[8]   = {1024,  512,   64, 2048, 1024, 2048, 2048, 2048};
    const int ntxs[8] = {  32,   16,    4,   64,   32,   64,   64,   64};
    int cum = 0;
    for (int i = 0; i < 8; ++i) {
        tp.src[i] = srcs[i]; tp.dst[i] = dsts[i];
        tp.K[i] = Ks[i]; tp.N[i] = Ns[i]; tp.ntx[i] = ntxs[i];
        tp.start[i] = cum;
        cum += ntxs[i] * (Ks[i] / 32);
    }
    tp.start[8] = cum;   // 12544 tiles

    const dim3 tb(32, 8);
    transpose_all<<<cum, tb, 0, stream>>>(tp);

    cast_f2b_k<<<(M_ * D_) / 1024, 256, 0, stream>>>(x, xb);

    // proj1: x @ [W_DQ | W_DKV | W_KR]  -> P1 (M x 1664)
    gemm_tn<1><<<dim3(1664/128, M_/128), 256, 0, stream>>>(xb, WT1, (void*)P1, 1664, 2048);

    // fused rmsnorm(q) + rmsnorm(kv) + rope_k
    normrope_k<<<dim3(M_, 3), 256, 0, stream>>>(P1, qnw, kvnw, cQb, cKVb, kRb);

    // proj2a: cQ @ [W_UQ | W_QR] -> P2;  proj2b: cKV @ [W_UK | W_UV] -> P3
    gemm_tn<1><<<dim3(3072/128, M_/128), 256, 0, stream>>>(cQb,  WT2, (void*)P2, 3072, 1024);
    gemm_tn<1><<<dim3(4096/128, M_/128), 256, 0, stream>>>(cKVb, WT3, (void*)P3, 4096, 512);

    rope_q_k<<<M_/2, 256, 0, stream>>>(P2, qRb, 3072, 2048);

    // V^T for MFMA B-operand: P3 cols 2048..4095 -> Vt (b, h*128+dv, T)
    transpose_b16<<<dim3(32, 32, B_), 256, 0, stream>>>(P3, Vt, 4096, 2048);

    // attn writes attn_out (=U1; P1 dead from here)
    attn_mfma_k<<<dim3(T_/ABQ, H_, B_), 512, 0, stream>>>(P2, qRb, P3, kRb, Vt, attn_out);

    // output projection -> d_out (fp32)
    gemm_tn<0><<<dim3(2048/128, M_/128), 256, 0, stream>>>(attn_out, WT_O, (void*)out, 2048, 2048);
}

// Round 10
// 440.931 us; speedup vs baseline: 1.0978x; 1.0655x over previous
//
#include <hip/hip_runtime.h>
#include <cstdint>
#include <cstddef>

// ---------------- problem constants ----------------
#define B_   2
#define T_   2048
#define D_   2048
#define H_   16
#define DH_  128
#define DQ_  1024
#define DKV_ 512
#define DR_  64
#define M_   4096            // B_*T_
#define SCALE_ 0.07216878364870323f   // 1/sqrt(DH_+DR_)
#define SC2_   0.10412808709930322f   // SCALE_ * log2(e)
#define LN_BASE_ 13.122363377404328f  // ln(500000)

typedef unsigned short u16;
typedef __attribute__((ext_vector_type(8))) short short8;   // 8 bf16 (4 VGPRs)
typedef __attribute__((ext_vector_type(4))) float f32x4;    // 4 fp32 acc

__device__ __forceinline__ float b2f(u16 u) { return __uint_as_float(((uint32_t)u) << 16); }
__device__ __forceinline__ u16 f2b(float f) {            // RNE
    uint32_t x = __float_as_uint(f);
    return (u16)((x + 0x7fffu + ((x >> 16) & 1u)) >> 16);
}
__device__ __forceinline__ u16 f2b_fast(float f) {       // round-up-ties, 2 ops
    return (u16)((__float_as_uint(f) + 0x8000u) >> 16);
}

// ---- fused prep: 8 weight transposes (+cast) AND x fp32->bf16, one launch ---
struct TPack {
    const float* src[8];
    u16*         dst[8];
    int K[8];      // src rows
    int N[8];      // src cols (real)
    int ntx[8];    // tiles along out-row dim (covers padded N)
    int start[9];  // cumulative tile offsets
};

__global__ __launch_bounds__(256) void prep_k(TPack p, const float* __restrict__ x,
                                              u16* __restrict__ xb, int ntr) {
    const int bid = blockIdx.x;
    if (bid < ntr) {
        __shared__ float tile[32][33];
        int w = 0;
#pragma unroll
        for (int i = 1; i < 8; ++i) if (bid >= p.start[i]) w = i;
        const int lt = bid - p.start[w];
        const int bx = lt % p.ntx[w], by = lt / p.ntx[w];
        const float* in = p.src[w];
        u16* out = p.dst[w];
        const int K = p.K[w], N = p.N[w];
        const int k0 = by * 32, n0 = bx * 32;
        const int tx = threadIdx.x & 31, ty = threadIdx.x >> 5;  // 32x8
#pragma unroll
        for (int i = 0; i < 4; ++i) {
            int k = k0 + ty + i * 8;
            int n = n0 + tx;
            tile[ty + i * 8][tx] = (n < N) ? in[(size_t)k * N + n] : 0.f;
        }
        __syncthreads();
#pragma unroll
        for (int i = 0; i < 4; ++i) {
            int n = n0 + ty + i * 8;     // out row
            out[(size_t)n * K + k0 + tx] = f2b(tile[tx][ty + i * 8]);
        }
    } else {
        const int i = ((bid - ntr) * 256 + threadIdx.x) * 4;
        const float4 v = *(const float4*)(x + i);
        ushort4 o;
        o.x = f2b(v.x); o.y = f2b(v.y); o.z = f2b(v.z); o.w = f2b(v.w);
        *(ushort4*)(xb + i) = o;
    }
}

// ---------------- bf16 GEMM:  C(MxN) = A(MxK) @ B(KxN), Bt given as NxK ------
template <int OUT_BF16>
__global__ __launch_bounds__(256) void gemm_tn(const u16* __restrict__ A,
                                               const u16* __restrict__ Bt,
                                               void* __restrict__ Cv,
                                               int N, int K) {
    __shared__ __attribute__((aligned(16))) u16 lA[128 * 32];
    __shared__ __attribute__((aligned(16))) u16 lB[128 * 32];
    const int m0 = blockIdx.y * 128, n0 = blockIdx.x * 128;
    const int tid = threadIdx.x, wave = tid >> 6, lane = tid & 63;
    const int wm = (wave >> 1) * 64, wn = (wave & 1) * 64;
    const int r = lane & 15, kq = lane >> 4;

    f32x4 acc[4][4];
#pragma unroll
    for (int i = 0; i < 4; ++i)
#pragma unroll
        for (int j = 0; j < 4; ++j) acc[i][j] = (f32x4){0.f, 0.f, 0.f, 0.f};

    for (int kk = 0; kk < K; kk += 32) {
#pragma unroll
        for (int p = 0; p < 2; ++p) {
            const int c = p * 256 + wave * 64 + lane;          // 16B chunk id
            const u16* ga = A  + (size_t)(m0 + (c >> 2)) * K + kk + (c & 3) * 8;
            const u16* gb = Bt + (size_t)(n0 + (c >> 2)) * K + kk + (c & 3) * 8;
            u16* la = lA + (size_t)(p * 256 + wave * 64) * 8;  // wave-uniform base
            u16* lb = lB + (size_t)(p * 256 + wave * 64) * 8;
            __builtin_amdgcn_global_load_lds(
                (const __attribute__((address_space(1))) uint32_t*)(uintptr_t)ga,
                (__attribute__((address_space(3))) uint32_t*)(uintptr_t)la, 16, 0, 0);
            __builtin_amdgcn_global_load_lds(
                (const __attribute__((address_space(1))) uint32_t*)(uintptr_t)gb,
                (__attribute__((address_space(3))) uint32_t*)(uintptr_t)lb, 16, 0, 0);
        }
        __syncthreads();
        short8 av[4], bv[4];
#pragma unroll
        for (int mi = 0; mi < 4; ++mi)
            av[mi] = *(const short8*)&lA[(wm + mi * 16 + r) * 32 + kq * 8];
#pragma unroll
        for (int ni = 0; ni < 4; ++ni)
            bv[ni] = *(const short8*)&lB[(wn + ni * 16 + r) * 32 + kq * 8];
#pragma unroll
        for (int mi = 0; mi < 4; ++mi)
#pragma unroll
            for (int ni = 0; ni < 4; ++ni)
                acc[mi][ni] = __builtin_amdgcn_mfma_f32_16x16x32_bf16(
                    av[mi], bv[ni], acc[mi][ni], 0, 0, 0);
        __syncthreads();
    }
    const int r4 = (lane >> 4) * 4, cc = lane & 15;
#pragma unroll
    for (int mi = 0; mi < 4; ++mi)
#pragma unroll
        for (int ni = 0; ni < 4; ++ni)
#pragma unroll
            for (int i = 0; i < 4; ++i) {
                const int row = m0 + wm + mi * 16 + r4 + i;
                const int col = n0 + wn + ni * 16 + cc;
                const float v = acc[mi][ni][i];
                if (OUT_BF16) ((u16*)Cv)[(size_t)row * N + col] = f2b(v);
                else          ((float*)Cv)[(size_t)row * N + col] = v;
            }
}

// ---- two bf16 GEMMs in ONE launch (block-range routed): both M=4096 --------
__global__ __launch_bounds__(256) void gemm_pair(const u16* __restrict__ A0,
                                                 const u16* __restrict__ B0,
                                                 u16* __restrict__ C0, int N0, int K0,
                                                 const u16* __restrict__ A1,
                                                 const u16* __restrict__ B1,
                                                 u16* __restrict__ C1, int N1, int K1,
                                                 int nx0) {
    __shared__ __attribute__((aligned(16))) u16 lA[128 * 32];
    __shared__ __attribute__((aligned(16))) u16 lB[128 * 32];
    const int sel = (int)blockIdx.x >= nx0;
    const u16* A  = sel ? A1 : A0;
    const u16* Bt = sel ? B1 : B0;
    u16* Cv = sel ? C1 : C0;
    const int N = sel ? N1 : N0, K = sel ? K1 : K0;
    const int bx = sel ? (blockIdx.x - nx0) : blockIdx.x;
    const int m0 = blockIdx.y * 128, n0 = bx * 128;
    const int tid = threadIdx.x, wave = tid >> 6, lane = tid & 63;
    const int wm = (wave >> 1) * 64, wn = (wave & 1) * 64;
    const int r = lane & 15, kq = lane >> 4;

    f32x4 acc[4][4];
#pragma unroll
    for (int i = 0; i < 4; ++i)
#pragma unroll
        for (int j = 0; j < 4; ++j) acc[i][j] = (f32x4){0.f, 0.f, 0.f, 0.f};

    for (int kk = 0; kk < K; kk += 32) {
#pragma unroll
        for (int p = 0; p < 2; ++p) {
            const int c = p * 256 + wave * 64 + lane;
            const u16* ga = A  + (size_t)(m0 + (c >> 2)) * K + kk + (c & 3) * 8;
            const u16* gb = Bt + (size_t)(n0 + (c >> 2)) * K + kk + (c & 3) * 8;
            u16* la = lA + (size_t)(p * 256 + wave * 64) * 8;
            u16* lb = lB + (size_t)(p * 256 + wave * 64) * 8;
            __builtin_amdgcn_global_load_lds(
                (const __attribute__((address_space(1))) uint32_t*)(uintptr_t)ga,
                (__attribute__((address_space(3))) uint32_t*)(uintptr_t)la, 16, 0, 0);
            __builtin_amdgcn_global_load_lds(
                (const __attribute__((address_space(1))) uint32_t*)(uintptr_t)gb,
                (__attribute__((address_space(3))) uint32_t*)(uintptr_t)lb, 16, 0, 0);
        }
        __syncthreads();
        short8 av[4], bv[4];
#pragma unroll
        for (int mi = 0; mi < 4; ++mi)
            av[mi] = *(const short8*)&lA[(wm + mi * 16 + r) * 32 + kq * 8];
#pragma unroll
        for (int ni = 0; ni < 4; ++ni)
            bv[ni] = *(const short8*)&lB[(wn + ni * 16 + r) * 32 + kq * 8];
#pragma unroll
        for (int mi = 0; mi < 4; ++mi)
#pragma unroll
            for (int ni = 0; ni < 4; ++ni)
                acc[mi][ni] = __builtin_amdgcn_mfma_f32_16x16x32_bf16(
                    av[mi], bv[ni], acc[mi][ni], 0, 0, 0);
        __syncthreads();
    }
    const int r4 = (lane >> 4) * 4, cc = lane & 15;
#pragma unroll
    for (int mi = 0; mi < 4; ++mi)
#pragma unroll
        for (int ni = 0; ni < 4; ++ni)
#pragma unroll
            for (int i = 0; i < 4; ++i) {
                const int row = m0 + wm + mi * 16 + r4 + i;
                const int col = n0 + wn + ni * 16 + cc;
                Cv[(size_t)row * N + col] = f2b(acc[mi][ni][i]);
            }
}

// ---- fused per-row ops on P1: rmsnorm(q), rmsnorm(kv), rope_k — one launch --
__global__ __launch_bounds__(256) void normrope_k(const u16* __restrict__ P1,
                                                  const float* __restrict__ qnw,
                                                  const float* __restrict__ kvnw,
                                                  u16* __restrict__ cQb,
                                                  u16* __restrict__ cKVb,
                                                  u16* __restrict__ kRb) {
    const int row = blockIdx.x;
    const int which = blockIdx.y;
    if (which < 2) {
        const int N = which ? 512 : 1024;
        const int off = which ? 1024 : 0;
        const float* w = which ? kvnw : qnw;
        u16* outp = which ? cKVb : cQb;
        const u16* src = P1 + (size_t)row * 1664 + off;
        const int j = threadIdx.x * 4;
        float v[4] = {0.f, 0.f, 0.f, 0.f};
        if (j < N) {
            ushort4 u = *(const ushort4*)(src + j);
            v[0] = b2f(u.x); v[1] = b2f(u.y); v[2] = b2f(u.z); v[3] = b2f(u.w);
        }
        float ss = v[0]*v[0] + v[1]*v[1] + v[2]*v[2] + v[3]*v[3];
#pragma unroll
        for (int offc = 32; offc; offc >>= 1) ss += __shfl_down(ss, offc);
        __shared__ float red[4];
        const int wave = threadIdx.x >> 6, lane = threadIdx.x & 63;
        if (lane == 0) red[wave] = ss;
        __syncthreads();
        const float tot = red[0] + red[1] + red[2] + red[3];
        const float sc = rsqrtf(tot / (float)N + 1e-6f);
        if (j < N) {
            ushort4 o;
            o.x = f2b(v[0] * sc * w[j]);
            o.y = f2b(v[1] * sc * w[j + 1]);
            o.z = f2b(v[2] * sc * w[j + 2]);
            o.w = f2b(v[3] * sc * w[j + 3]);
            *(ushort4*)(outp + (size_t)row * N + j) = o;
        }
    } else {
        const int j = threadIdx.x;               // only 0..63 active
        if (j < 64) {
            const int t = row & (T_ - 1);
            const int i = j & 31;
            const float invf = __expf(-LN_BASE_ * (float)(2 * i) * (1.0f / 64.0f));
            const float ang = (float)t * invf;
            const float c = cosf(ang), s = sinf(ang);
            const u16* src = P1 + (size_t)row * 1664 + 1536;
            const float v = b2f(src[j]);
            const float rot = (j < 32) ? -b2f(src[j + 32]) : b2f(src[j - 32]);
            kRb[(size_t)row * 64 + j] = f2b(v * c + rot * s);
        }
    }
}

// ---- fused epilog2: RoPE(q) [2048 blocks] + V^T transpose [2048 blocks] ----
__global__ __launch_bounds__(256) void epilog2_k(const u16* __restrict__ P2,
                                                 u16* __restrict__ qRb,
                                                 const u16* __restrict__ P3,
                                                 u16* __restrict__ Vt) {
    const int bid = blockIdx.x;
    if (bid < 2048) {
        // RoPE for q: rows 2*bid, 2*bid+1; 8xu16 vectorized
        const int row = bid * 2 + (threadIdx.x >> 7);
        const int t = row & (T_ - 1);
        const int e0 = (threadIdx.x & 127) * 8;
        const u16* src = P2 + (size_t)row * 3072 + 2048;
        const int j0 = e0 & 63;
        const ushort4* pv = (const ushort4*)(src + e0);
        const ushort4* pr = (const ushort4*)(src + (j0 < 32 ? e0 + 32 : e0 - 32));
        const float sgn = (j0 < 32) ? -1.f : 1.f;
        ushort4 v01 = pv[0], v23 = pv[1];
        ushort4 r01 = pr[0], r23 = pr[1];
        const u16 vv[8] = {v01.x, v01.y, v01.z, v01.w, v23.x, v23.y, v23.z, v23.w};
        const u16 rr[8] = {r01.x, r01.y, r01.z, r01.w, r23.x, r23.y, r23.z, r23.w};
        u16 o[8];
#pragma unroll
        for (int k = 0; k < 8; ++k) {
            const int i = (j0 + k) & 31;
            const float invf = __expf(-LN_BASE_ * (float)(2 * i) * (1.0f / 64.0f));
            const float ang = (float)t * invf;
            o[k] = f2b(b2f(vv[k]) * cosf(ang) + sgn * b2f(rr[k]) * sinf(ang));
        }
        *(uint4*)(qRb + (size_t)row * 1024 + e0) = *(uint4*)o;
    } else {
        // V^T: P3[:, 2048+c] -> Vt (b, c, T); 64x64 tiles, 16B both sides
        __shared__ u16 tile[64][72];
        const int tt = bid - 2048;
        const int b = tt >> 10;
        const int rem = tt & 1023;
        const int by = rem >> 5, bx = rem & 31;
        const int t0 = by * 64, c0 = bx * 64;
        const int tid = threadIdx.x;
        const int rr2 = tid >> 3;        // 0..31
        const int c8 = tid & 7;          // 16B chunk within 64
#pragma unroll
        for (int p = 0; p < 2; ++p) {
            const int row = p * 32 + rr2;
            *(uint4*)&tile[row][c8 * 8] =
                *(const uint4*)(P3 + (size_t)(b * T_ + t0 + row) * 4096 + 2048 + c0 + c8 * 8);
        }
        __syncthreads();
#pragma unroll
        for (int p = 0; p < 2; ++p) {
            const int c = p * 32 + rr2;
            u16 tmp[8];
#pragma unroll
            for (int j = 0; j < 8; ++j) tmp[j] = tile[c8 * 8 + j][c];
            *(uint4*)(Vt + ((size_t)b * 2048 + c0 + c) * 2048 + t0 + c8 * 8) = *(uint4*)tmp;
        }
    }
}

// ---------------- MFMA flash attention (causal, d=192, dv=128) --------------
// R7-proven structure: 256 thr = 4 waves x 32 q-rows; BK=64; no-max softmax
// (p=exp2(S*SC2), L additive per-lane, one epilogue reduce); wave-uniform
// causal-mask split; causal-balanced qb pairing.
#define ABQ  128
#define ABK  64
#define KSTR 200   // sK row stride u16
#define VSTR 72    // sV row stride u16
#define PSTR 72    // sP row stride u16
#define QSTRIDE 3072   // P2 row stride (qC cols 0..2047)
#define KSTRIDE 4096   // P3 row stride (kC cols 0..2047)

__global__ __launch_bounds__(256, 2) void attn_mfma_k(
    const u16* __restrict__ qC, const u16* __restrict__ qR,
    const u16* __restrict__ kC, const u16* __restrict__ kR,
    const u16* __restrict__ Vt, u16* __restrict__ outp)
{
    __shared__ __attribute__((aligned(16))) u16 sK[64 * KSTR];    // 25.0 KB
    __shared__ __attribute__((aligned(16))) u16 sV[128 * VSTR];   // 18.0 KB
    __shared__ __attribute__((aligned(16))) u16 sP[4 * 32 * PSTR];// 18.0 KB

    const int h = blockIdx.y, b = blockIdx.z;
    const int qb = b ? (15 - blockIdx.x) : blockIdx.x;   // causal balance
    const int q0 = qb * ABQ;
    const int tid = threadIdx.x, wave = tid >> 6, lane = tid & 63;
    const int r = lane & 15, kq = lane >> 4, r4 = kq * 4;
    const int wq = wave * 32;

    // Q fragments (A-layout) in registers: [mt][kc], k = kc*32 + kq*8 + j
    short8 qf[2][6];
#pragma unroll
    for (int mt = 0; mt < 2; ++mt) {
        const int t = q0 + wq + mt * 16 + r;
        const u16* qcrow = qC + (size_t)(b * T_ + t) * QSTRIDE + h * 128 + kq * 8;
        const u16* qrrow = qR + (size_t)(b * T_ + t) * 1024 + h * 64 + kq * 8;
#pragma unroll
        for (int kc = 0; kc < 4; ++kc) qf[mt][kc] = *(const short8*)(qcrow + kc * 32);
#pragma unroll
        for (int kc = 0; kc < 2; ++kc) qf[mt][4 + kc] = *(const short8*)(qrrow + kc * 32);
    }

    f32x4 Oa[2][8];
#pragma unroll
    for (int mt = 0; mt < 2; ++mt)
#pragma unroll
        for (int nt = 0; nt < 8; ++nt) Oa[mt][nt] = (f32x4){0.f, 0.f, 0.f, 0.f};
    float Lrow[2][4] = {{0.f,0.f,0.f,0.f},{0.f,0.f,0.f,0.f}};

    u16* myP = sP + wave * 32 * PSTR;

    const int nkt = 2 * qb + 2;
    for (int kt = 0; kt < nkt; ++kt) {
        const int k0 = kt * ABK;
        // ---- stage K tile: slots s = row*25 + chunk, 25 instr x 1KB
        for (int i = wave; i < 25; i += 4) {
            const int s = i * 64 + lane;
            const int rr = s / 25;
            int cc = s - rr * 25;
            if (cc > 23) cc = 0;                       // pad slot: harmless dup
            const int t = k0 + rr;
            const u16* src = (cc < 16)
                ? kC + (size_t)(b * T_ + t) * KSTRIDE + h * 128 + cc * 8
                : kR + (size_t)(b * T_ + t) * 64 + (cc - 16) * 8;
            __builtin_amdgcn_global_load_lds(
                (const __attribute__((address_space(1))) uint32_t*)(uintptr_t)src,
                (__attribute__((address_space(3))) uint32_t*)(uintptr_t)(sK + i * 512),
                16, 0, 0);
        }
        // ---- stage V^T tile: slots s = dv*9 + chunk, 18 instr
        for (int i = wave; i < 18; i += 4) {
            const int s = i * 64 + lane;
            const int rr = s / 9;
            int cc = s - rr * 9;
            if (cc > 7) cc = 0;                        // pad slot
            const u16* src = Vt + ((size_t)(b * H_ + h) * 128 + rr) * T_ + k0 + cc * 8;
            __builtin_amdgcn_global_load_lds(
                (const __attribute__((address_space(1))) uint32_t*)(uintptr_t)src,
                (__attribute__((address_space(3))) uint32_t*)(uintptr_t)(sV + i * 512),
                16, 0, 0);
        }
        __syncthreads();

        // ---- S = Q K^T  (48 MFMA/wave)
        f32x4 Sa[2][4];
#pragma unroll
        for (int mt = 0; mt < 2; ++mt)
#pragma unroll
            for (int nt = 0; nt < 4; ++nt) Sa[mt][nt] = (f32x4){0.f, 0.f, 0.f, 0.f};
#pragma unroll
        for (int kc = 0; kc < 6; ++kc) {
            short8 kf[4];
#pragma unroll
            for (int nt = 0; nt < 4; ++nt)
                kf[nt] = *(const short8*)&sK[(nt * 16 + r) * KSTR + (kc * 4 + kq) * 8];
#pragma unroll
            for (int mt = 0; mt < 2; ++mt)
#pragma unroll
                for (int nt = 0; nt < 4; ++nt)
                    Sa[mt][nt] = __builtin_amdgcn_mfma_f32_16x16x32_bf16(
                        qf[mt][kc], kf[nt], Sa[mt][nt], 0, 0, 0);
        }

        // ---- no-max softmax: p = exp2(S*SC2); wave-uniform mask split
        if (kt < nkt - 2) {
#pragma unroll
            for (int mt = 0; mt < 2; ++mt)
#pragma unroll
                for (int i = 0; i < 4; ++i) {
                    float sm = 0.f;
                    float p[4];
#pragma unroll
                    for (int nt = 0; nt < 4; ++nt) {
                        p[nt] = exp2f(Sa[mt][nt][i] * SC2_);
                        sm += p[nt];
                    }
                    Lrow[mt][i] += sm;
#pragma unroll
                    for (int nt = 0; nt < 4; ++nt)
                        myP[(mt * 16 + r4 + i) * PSTR + nt * 16 + r] = f2b_fast(p[nt]);
                }
        } else {
#pragma unroll
            for (int mt = 0; mt < 2; ++mt)
#pragma unroll
                for (int i = 0; i < 4; ++i) {
                    const int grow = q0 + wq + mt * 16 + r4 + i;
                    float sm = 0.f;
                    float p[4];
#pragma unroll
                    for (int nt = 0; nt < 4; ++nt) {
                        float pv = exp2f(Sa[mt][nt][i] * SC2_);
                        p[nt] = (k0 + nt * 16 + r > grow) ? 0.f : pv;
                        sm += p[nt];
                    }
                    Lrow[mt][i] += sm;
#pragma unroll
                    for (int nt = 0; nt < 4; ++nt)
                        myP[(mt * 16 + r4 + i) * PSTR + nt * 16 + r] = f2b_fast(p[nt]);
                }
        }

        // ---- O += P V  (P is wave-local; HW lgkmcnt orders write->read)
#pragma unroll
        for (int kc2 = 0; kc2 < 2; ++kc2) {
            short8 pf[2];
#pragma unroll
            for (int mt = 0; mt < 2; ++mt)
                pf[mt] = *(const short8*)&myP[(mt * 16 + r) * PSTR + (kc2 * 4 + kq) * 8];
#pragma unroll
            for (int nt = 0; nt < 8; ++nt) {
                const short8 vf = *(const short8*)&sV[(nt * 16 + r) * VSTR + (kc2 * 4 + kq) * 8];
#pragma unroll
                for (int mt = 0; mt < 2; ++mt)
                    Oa[mt][nt] = __builtin_amdgcn_mfma_f32_16x16x32_bf16(
                        pf[mt], vf, Oa[mt][nt], 0, 0, 0);
            }
        }
        __syncthreads();
    }

    // ---- epilogue: reduce L across the 16 lanes of each quad-group, O /= L
#pragma unroll
    for (int mt = 0; mt < 2; ++mt)
#pragma unroll
        for (int i = 0; i < 4; ++i) {
            float L = Lrow[mt][i];
            L += __shfl_xor(L, 1);
            L += __shfl_xor(L, 2);
            L += __shfl_xor(L, 4);
            L += __shfl_xor(L, 8);
            const float inv = 1.0f / L;
            const int t = q0 + wq + mt * 16 + r4 + i;
            u16* orow = outp + (size_t)(b * T_ + t) * 2048 + h * 128;
#pragma unroll
            for (int nt = 0; nt < 8; ++nt)
                orow[nt * 16 + r] = f2b(Oa[mt][nt][i] * inv);
        }
}

// ---------------- host side -------------------------------------------------
// Workspace plan: 139.46 MB (proven safe; 153 MB OOB'd in round 4).
// U1 time-shared: P1 (phase 1) then attn_out (phase 3). Vt reuses xb.
// 7 dispatches: prep -> proj1 -> normrope -> proj2(pair) -> epilog2 -> attn -> WO
extern "C" void kernel_launch(void* const* d_in, const int* in_sizes, int n_in,
                              void* d_out, int out_size, void* d_ws, size_t ws_size,
                              hipStream_t stream) {
    (void)in_sizes; (void)n_in; (void)out_size; (void)ws_size;
    const float* x     = (const float*)d_in[0];
    const float* W_DQ  = (const float*)d_in[1];
    const float* W_UQ  = (const float*)d_in[2];
    const float* W_QR  = (const float*)d_in[3];
    const float* W_DKV = (const float*)d_in[4];
    const float* W_UK  = (const float*)d_in[5];
    const float* W_UV  = (const float*)d_in[6];
    const float* W_KR  = (const float*)d_in[7];
    const float* W_O   = (const float*)d_in[8];
    const float* qnw   = (const float*)d_in[9];
    const float* kvnw  = (const float*)d_in[10];
    float* out = (float*)d_out;   // fp32 output per reference dtype

    char* base = (char*)d_ws;
    size_t o = 0;
    auto alloc = [&](size_t bytes) {
        char* r = base + o;
        o += (bytes + 255) & ~(size_t)255;
        return r;
    };
    u16* WT1  = (u16*)alloc((size_t)1664 * 2048 * 2);
    u16* WT2  = (u16*)alloc((size_t)3072 * 1024 * 2);
    u16* WT3  = (u16*)alloc((size_t)4096 * 512 * 2);
    u16* WT_O = (u16*)alloc((size_t)2048 * 2048 * 2);
    u16* xb   = (u16*)alloc((size_t)M_ * 2048 * 2);    // x bf16; later Vt
    u16* U1   = (u16*)alloc((size_t)M_ * 2048 * 2);    // P1 then attn_out
    u16* P2   = (u16*)alloc((size_t)M_ * 3072 * 2);    // [qC | qR_raw]
    u16* P3   = (u16*)alloc((size_t)M_ * 4096 * 2);    // [kC | vC]
    u16* cQb  = (u16*)alloc((size_t)M_ * 1024 * 2);
    u16* cKVb = (u16*)alloc((size_t)M_ * 512 * 2);
    u16* qRb  = (u16*)alloc((size_t)M_ * 1024 * 2);
    u16* kRb  = (u16*)alloc((size_t)M_ * 64 * 2);
    u16* P1       = U1;
    u16* attn_out = U1;
    u16* Vt       = xb;

    // ---- dispatch 1: all 8 weight transposes + x cast
    TPack tp;
    const float* srcs[8] = {W_DQ, W_DKV, W_KR, W_UQ, W_QR, W_UK, W_UV, W_O};
    u16* dsts[8] = {WT1, WT1 + (size_t)1024*2048, WT1 + (size_t)1536*2048,
                    WT2, WT2 + (size_t)2048*1024,
                    WT3, WT3 + (size_t)2048*512, WT_O};
    const int Ks[8]   = {2048, 2048, 2048, 1024, 1024, 512, 512, 2048};
    const int Ns[8]   = {1024,  512,   64, 2048, 1024, 2048, 2048, 2048};
    const int ntxs[8] = {  32,   16,    4,   64,   32,   64,   64,   64};
    int cum = 0;
    for (int i = 0; i < 8; ++i) {
        tp.src[i] = srcs[i]; tp.dst[i] = dsts[i];
        tp.K[i] = Ks[i]; tp.N[i] = Ns[i]; tp.ntx[i] = ntxs[i];
        tp.start[i] = cum;
        cum += ntxs[i] * (Ks[i] / 32);
    }
    tp.start[8] = cum;   // 12544 transpose tiles
    const int ncast = (M_ * D_) / 1024;   // 8192 cast blocks
    prep_k<<<cum + ncast, 256, 0, stream>>>(tp, x, xb, cum);

    // ---- dispatch 2: proj1: x @ [W_DQ | W_DKV | W_KR] -> P1 (M x 1664)
    gemm_tn<1><<<dim3(1664/128, M_/128), 256, 0, stream>>>(xb, WT1, (void*)P1, 1664, 2048);

    // ---- dispatch 3: fused rmsnorm(q) + rmsnorm(kv) + rope_k
    normrope_k<<<dim3(M_, 3), 256, 0, stream>>>(P1, qnw, kvnw, cQb, cKVb, kRb);

    // ---- dispatch 4: proj2a (cQ @ [W_UQ|W_QR] -> P2) + proj2b (cKV @ [W_UK|W_UV] -> P3)
    gemm_pair<<<dim3(3072/128 + 4096/128, M_/128), 256, 0, stream>>>(
        cQb,  WT2, P2, 3072, 1024,
        cKVb, WT3, P3, 4096, 512,
        3072/128);

    // ---- dispatch 5: RoPE(q) + V^T transpose
    epilog2_k<<<4096, 256, 0, stream>>>(P2, qRb, P3, Vt);

    // ---- dispatch 6: attention (writes attn_out = U1; P1 dead from here)
    attn_mfma_k<<<dim3(T_/ABQ, H_, B_), 256, 0, stream>>>(P2, qRb, P3, kRb, Vt, attn_out);

    // ---- dispatch 7: output projection -> d_out (fp32)
    gemm_tn<0><<<dim3(2048/128, M_/128), 256, 0, stream>>>(attn_out, WT_O, (void*)out, 2048, 2048);
}